// Round 2
// baseline (1915.829 us; speedup 1.0000x reference)
//
#include <hip/hip_runtime.h>
#include <hip/hip_bf16.h>
#include <cstdint>
#include <cstddef>

#define N_NODES 50000
#define N_EDGES 800000
#define IN_DIM 256
#define H1 640
#define H2 320
#define OUT_DIM 128

typedef unsigned short u16;

__device__ __forceinline__ float b2f(u16 u) {
    union { unsigned int i; float f; } v; v.i = ((unsigned int)u) << 16; return v.f;
}
__device__ __forceinline__ u16 f2b(float f) {
    __hip_bfloat16 h = __float2bfloat16(f);
    return *reinterpret_cast<u16*>(&h);
}

// ---------------------------------------------------------------------------
// CSR build
// ---------------------------------------------------------------------------

__global__ void zero2_kernel(int* __restrict__ a, int* __restrict__ b, int n) {
    int i = blockIdx.x * blockDim.x + threadIdx.x;
    if (i < n) { a[i] = 0; b[i] = 0; }
}

__global__ void count_deg_kernel(const int* __restrict__ dst, int* __restrict__ cnt, int nE) {
    int i = blockIdx.x * blockDim.x + threadIdx.x;
    if (i < nE) atomicAdd(&cnt[dst[i]], 1);
}

__global__ __launch_bounds__(1024)
void scan_deg_kernel(const int* __restrict__ cnt, int* __restrict__ row_ptr,
                     float* __restrict__ inv_deg) {
    const int NT = 1024, N = N_NODES;
    const int CH = (N + NT - 1) / NT;
    __shared__ int part[NT];
    int tid = threadIdx.x;
    int s0 = tid * CH;
    int s1 = s0 + CH; if (s1 > N) s1 = N;
    if (s0 > N) s0 = N;
    int s = 0;
    for (int i = s0; i < s1; ++i) s += cnt[i];
    part[tid] = s;
    __syncthreads();
    for (int off = 1; off < NT; off <<= 1) {
        int v = 0;
        if (tid >= off) v = part[tid - off];
        __syncthreads();
        if (tid >= off) part[tid] += v;
        __syncthreads();
    }
    int run = (tid == 0) ? 0 : part[tid - 1];
    for (int i = s0; i < s1; ++i) {
        row_ptr[i] = run;
        int c = cnt[i];
        inv_deg[i] = (c > 0) ? (1.0f / (float)c) : 0.0f;
        run += c;
    }
    if (tid == NT - 1) row_ptr[N] = run;
}

__global__ void scatter_kernel(const int* __restrict__ src, const int* __restrict__ dst,
                               const int* __restrict__ row_ptr, int* __restrict__ cursor,
                               int* __restrict__ csr_src, int nE) {
    int i = blockIdx.x * blockDim.x + threadIdx.x;
    if (i < nE) {
        int d = dst[i];
        int p = atomicAdd(&cursor[d], 1);
        csr_src[row_ptr[d] + p] = src[i];
    }
}

// ---------------------------------------------------------------------------
// f32 -> bf16 cast (vectorized)
// ---------------------------------------------------------------------------

__global__ void cast_kernel(const float4* __restrict__ in, ushort4* __restrict__ out, int n4) {
    int i = blockIdx.x * blockDim.x + threadIdx.x;
    if (i < n4) {
        float4 v = in[i];
        ushort4 o;
        o.x = f2b(v.x); o.y = f2b(v.y); o.z = f2b(v.z); o.w = f2b(v.w);
        out[i] = o;
    }
}

// ---------------------------------------------------------------------------
// Mean aggregation over in-neighbors (bf16 in, f32 accumulate, bf16 out)
// one block (256 threads) per destination node
// ---------------------------------------------------------------------------

template<int D>
__global__ __launch_bounds__(256)
void aggregate_kernel(const u16* __restrict__ h, const int* __restrict__ row_ptr,
                      const int* __restrict__ csr_src, const float* __restrict__ inv_deg,
                      u16* __restrict__ out) {
    constexpr int C = (D + 255) / 256;
    int node = blockIdx.x;
    int tid = threadIdx.x;
    if (D < 256 && tid >= D) return;
    int e0 = row_ptr[node], e1 = row_ptr[node + 1];
    float acc[C];
#pragma unroll
    for (int c = 0; c < C; ++c) acc[c] = 0.0f;
    for (int e = e0; e < e1; ++e) {
        int s = csr_src[e];
        const u16* hp = h + (size_t)s * D;
#pragma unroll
        for (int c = 0; c < C; ++c) {
            int col = tid + c * 256;
            if (col < D) acc[c] += b2f(hp[col]);
        }
    }
    float wgt = inv_deg[node];
    u16* op = out + (size_t)node * D;
#pragma unroll
    for (int c = 0; c < C; ++c) {
        int col = tid + c * 256;
        if (col < D) op[col] = f2b(acc[c] * wgt);
    }
}

// ---------------------------------------------------------------------------
// Fused GEMM:  C = [elu]( A@W0 [+ G@W1] [+ ADD] [+ bias] )
// A,G,ADD bf16 (row-major, K / N strides), W f32 [K x N], out bf16 or f32.
// BM=64 BN=64 BK=16, 256 threads, 4x4 per thread. N %64==0, K %16==0, M ragged.
// ---------------------------------------------------------------------------

template<bool DUAL, bool HASADD, bool FIN, bool OUTF32>
__global__ __launch_bounds__(256)
void gemm_kernel(const u16* __restrict__ A, const u16* __restrict__ G,
                 const float* __restrict__ W0, const float* __restrict__ W1,
                 const u16* __restrict__ ADD, const float* __restrict__ bias,
                 void* __restrict__ Cout, int M, int K, int N) {
    const int BM = 64, BN = 64, BK = 16;
    __shared__ float As[BK][BM + 1];
    __shared__ float Gs[BK][BM + 1];
    __shared__ float Bs[BK][BN];
    __shared__ float Ns[BK][BN];
    int tid = threadIdx.x;
    int rowBase = blockIdx.y * BM, colBase = blockIdx.x * BN;
    int lar = tid >> 2;            // 0..63 : row within A tile
    int lak = (tid & 3) << 2;      // k quad
    int lbk = tid >> 4;            // 0..15 : k within B tile
    int lbc = (tid & 15) << 2;     // col quad
    int tx = tid & 15, ty = tid >> 4;
    float acc[4][4] = {{0.0f}};

    for (int k0 = 0; k0 < K; k0 += BK) {
        int arow = rowBase + lar;
        ushort4 av = make_ushort4(0, 0, 0, 0);
        ushort4 gv = av;
        if (arow < M) {
            av = *(const ushort4*)(A + (size_t)arow * K + k0 + lak);
            if (DUAL) gv = *(const ushort4*)(G + (size_t)arow * K + k0 + lak);
        }
        As[lak + 0][lar] = b2f(av.x); As[lak + 1][lar] = b2f(av.y);
        As[lak + 2][lar] = b2f(av.z); As[lak + 3][lar] = b2f(av.w);
        if (DUAL) {
            Gs[lak + 0][lar] = b2f(gv.x); Gs[lak + 1][lar] = b2f(gv.y);
            Gs[lak + 2][lar] = b2f(gv.z); Gs[lak + 3][lar] = b2f(gv.w);
        }
        *(float4*)&Bs[lbk][lbc] = *(const float4*)(W0 + (size_t)(k0 + lbk) * N + colBase + lbc);
        if (DUAL)
            *(float4*)&Ns[lbk][lbc] = *(const float4*)(W1 + (size_t)(k0 + lbk) * N + colBase + lbc);
        __syncthreads();

#pragma unroll
        for (int k = 0; k < BK; ++k) {
            float a[4], b[4];
#pragma unroll
            for (int i = 0; i < 4; ++i) a[i] = As[k][ty * 4 + i];
#pragma unroll
            for (int j = 0; j < 4; ++j) b[j] = Bs[k][tx * 4 + j];
#pragma unroll
            for (int i = 0; i < 4; ++i)
#pragma unroll
                for (int j = 0; j < 4; ++j)
                    acc[i][j] += a[i] * b[j];
            if (DUAL) {
                float g[4], n[4];
#pragma unroll
                for (int i = 0; i < 4; ++i) g[i] = Gs[k][ty * 4 + i];
#pragma unroll
                for (int j = 0; j < 4; ++j) n[j] = Ns[k][tx * 4 + j];
#pragma unroll
                for (int i = 0; i < 4; ++i)
#pragma unroll
                    for (int j = 0; j < 4; ++j)
                        acc[i][j] += g[i] * n[j];
            }
        }
        __syncthreads();
    }

    int col0 = colBase + tx * 4;
    float bi[4] = {0.f, 0.f, 0.f, 0.f};
    if (FIN) {
#pragma unroll
        for (int j = 0; j < 4; ++j) bi[j] = bias[col0 + j];
    }
#pragma unroll
    for (int i = 0; i < 4; ++i) {
        int row = rowBase + ty * 4 + i;
        if (row >= M) continue;
        float v[4];
#pragma unroll
        for (int j = 0; j < 4; ++j) v[j] = acc[i][j] + bi[j];
        if (HASADD) {
            ushort4 ad = *(const ushort4*)(ADD + (size_t)row * N + col0);
            v[0] += b2f(ad.x); v[1] += b2f(ad.y); v[2] += b2f(ad.z); v[3] += b2f(ad.w);
        }
        if (FIN) {
#pragma unroll
            for (int j = 0; j < 4; ++j) v[j] = (v[j] > 0.0f) ? v[j] : expm1f(v[j]);
        }
        if (OUTF32) {
            float4 o = make_float4(v[0], v[1], v[2], v[3]);
            *(float4*)((float*)Cout + (size_t)row * N + col0) = o;
        } else {
            ushort4 o = make_ushort4(f2b(v[0]), f2b(v[1]), f2b(v[2]), f2b(v[3]));
            *(ushort4*)((u16*)Cout + (size_t)row * N + col0) = o;
        }
    }
}

// ---------------------------------------------------------------------------

extern "C" void kernel_launch(void* const* d_in, const int* in_sizes, int n_in,
                              void* d_out, int out_size, void* d_ws, size_t ws_size,
                              hipStream_t stream) {
    const float* features = (const float*)d_in[0];
    const int*   edge_src = (const int*)d_in[1];
    const int*   edge_dst = (const int*)d_in[2];
    const float* W1s = (const float*)d_in[3];
    const float* W1n = (const float*)d_in[4];
    const float* b1  = (const float*)d_in[5];
    const float* W2s = (const float*)d_in[6];
    const float* W2n = (const float*)d_in[7];
    const float* b2  = (const float*)d_in[8];
    const float* W3s = (const float*)d_in[9];
    const float* W3n = (const float*)d_in[10];
    const float* b3  = (const float*)d_in[11];
    const float* Wres = (const float*)d_in[12];
    const float* bres = (const float*)d_in[13];

    float* out_x   = (float*)d_out;
    float* out_res = out_x + (size_t)N_NODES * OUT_DIM;

    // ---- workspace layout (offsets, 256B aligned) ----
    size_t off = 0;
    auto carve = [&](size_t bytes) {
        size_t p = off;
        off += (bytes + 255) & ~(size_t)255;
        return p;
    };
    size_t o_cnt     = carve((size_t)N_NODES * 4);
    size_t o_rowptr  = carve((size_t)(N_NODES + 1) * 4);
    size_t o_cursor  = carve((size_t)N_NODES * 4);
    size_t o_invdeg  = carve((size_t)N_NODES * 4);
    size_t o_csr     = carve((size_t)N_EDGES * 4);
    // regionA: fX(25.6M) + aggF(25.6M); later x2(32M) at regionA base
    size_t o_regA    = carve((size_t)N_NODES * (IN_DIM + IN_DIM) * 2);
    // regionB: x1(64M); later Y3(12.8M)@+0 and A3(12.8M)@+12.8M
    size_t o_regB    = carve((size_t)N_NODES * H1 * 2);
    // regionC: Y2(32M)
    size_t o_regC    = carve((size_t)N_NODES * H2 * 2);
    // regionD: A2(32M)
    size_t o_regD    = carve((size_t)N_NODES * H2 * 2);
    size_t REQUIRED  = off;
    if (ws_size < REQUIRED) return;   // diagnostic: stub-like failure => ws too small

    char* W = (char*)d_ws;
    int*   cnt     = (int*)(W + o_cnt);
    int*   row_ptr = (int*)(W + o_rowptr);
    int*   cursor  = (int*)(W + o_cursor);
    float* inv_deg = (float*)(W + o_invdeg);
    int*   csr_src = (int*)(W + o_csr);
    u16*   fX      = (u16*)(W + o_regA);
    u16*   aggF    = fX + (size_t)N_NODES * IN_DIM;
    u16*   x2      = (u16*)(W + o_regA);            // aliases fX+aggF (dead by then)
    u16*   x1      = (u16*)(W + o_regB);
    u16*   Y3      = (u16*)(W + o_regB);            // aliases x1 (dead by then)
    u16*   A3      = Y3 + (size_t)N_NODES * OUT_DIM;
    u16*   Y2      = (u16*)(W + o_regC);
    u16*   A2      = (u16*)(W + o_regD);

    const int mblocks = (N_NODES + 63) / 64;

    // ---- CSR build ----
    zero2_kernel<<<(N_NODES + 255) / 256, 256, 0, stream>>>(cnt, cursor, N_NODES);
    count_deg_kernel<<<(N_EDGES + 255) / 256, 256, 0, stream>>>(edge_dst, cnt, N_EDGES);
    scan_deg_kernel<<<1, 1024, 0, stream>>>(cnt, row_ptr, inv_deg);
    scatter_kernel<<<(N_EDGES + 255) / 256, 256, 0, stream>>>(edge_src, edge_dst, row_ptr,
                                                              cursor, csr_src, N_EDGES);

    // ---- cast features to bf16 ----
    {
        int n4 = N_NODES * IN_DIM / 4;
        cast_kernel<<<(n4 + 255) / 256, 256, 0, stream>>>((const float4*)features,
                                                          (ushort4*)fX, n4);
    }

    // ---- residual head: res = elu(fX@Wres + bres) -> out_res (f32) ----
    {
        dim3 g(OUT_DIM / 64, mblocks);
        gemm_kernel<false, false, true, true><<<g, 256, 0, stream>>>(
            fX, nullptr, Wres, nullptr, nullptr, bres, out_res, N_NODES, IN_DIM, OUT_DIM);
    }

    // ---- layer 1 (aggregate-before: in-dim 256 < out-dim 640) ----
    aggregate_kernel<IN_DIM><<<N_NODES, 256, 0, stream>>>(fX, row_ptr, csr_src, inv_deg, aggF);
    {
        dim3 g(H1 / 64, mblocks);
        gemm_kernel<true, false, true, false><<<g, 256, 0, stream>>>(
            fX, aggF, W1s, W1n, nullptr, b1, x1, N_NODES, IN_DIM, H1);
    }

    // ---- layer 2 (aggregate-after: S(x1@W2n), since 320 < 640) ----
    {
        dim3 g(H2 / 64, mblocks);
        gemm_kernel<false, false, false, false><<<g, 256, 0, stream>>>(
            x1, nullptr, W2n, nullptr, nullptr, nullptr, Y2, N_NODES, H1, H2);
    }
    aggregate_kernel<H2><<<N_NODES, 256, 0, stream>>>(Y2, row_ptr, csr_src, inv_deg, A2);
    {
        dim3 g(H2 / 64, mblocks);
        gemm_kernel<false, true, true, false><<<g, 256, 0, stream>>>(
            x1, nullptr, W2s, nullptr, A2, b2, x2, N_NODES, H1, H2);
    }

    // ---- layer 3 (aggregate-after: 128 < 320) ----
    {
        dim3 g(OUT_DIM / 64, mblocks);
        gemm_kernel<false, false, false, false><<<g, 256, 0, stream>>>(
            x2, nullptr, W3n, nullptr, nullptr, nullptr, Y3, N_NODES, H2, OUT_DIM);
    }
    aggregate_kernel<OUT_DIM><<<N_NODES, 256, 0, stream>>>(Y3, row_ptr, csr_src, inv_deg, A3);
    {
        dim3 g(OUT_DIM / 64, mblocks);
        gemm_kernel<false, true, true, true><<<g, 256, 0, stream>>>(
            x2, nullptr, W3s, nullptr, A3, b3, out_x, N_NODES, H2, OUT_DIM);
    }
}

// Round 3
// 1161.969 us; speedup vs baseline: 1.6488x; 1.6488x over previous
//
#include <hip/hip_runtime.h>
#include <hip/hip_bf16.h>
#include <cstdint>
#include <cstddef>

#define N_NODES 50000
#define N_EDGES 800000
#define IN_DIM 256
#define H1 640
#define H2 320
#define OUT_DIM 128

typedef unsigned short u16;
typedef __attribute__((ext_vector_type(8))) short short8v;   // 8 bf16 = 4 VGPR
typedef __attribute__((ext_vector_type(4))) float float4v;   // MFMA C/D

__device__ __forceinline__ float b2f(u16 u) {
    union { unsigned int i; float f; } v; v.i = ((unsigned int)u) << 16; return v.f;
}
__device__ __forceinline__ u16 f2b(float f) {
    __hip_bfloat16 h = __float2bfloat16(f);
    return *reinterpret_cast<u16*>(&h);
}

// ---------------------------------------------------------------------------
// CSR build
// ---------------------------------------------------------------------------

__global__ void zero2_kernel(int* __restrict__ a, int* __restrict__ b, int n) {
    int i = blockIdx.x * blockDim.x + threadIdx.x;
    if (i < n) { a[i] = 0; b[i] = 0; }
}

__global__ void count_deg_kernel(const int* __restrict__ dst, int* __restrict__ cnt, int nE) {
    int i = blockIdx.x * blockDim.x + threadIdx.x;
    if (i < nE) atomicAdd(&cnt[dst[i]], 1);
}

__global__ __launch_bounds__(1024)
void scan_deg_kernel(const int* __restrict__ cnt, int* __restrict__ row_ptr,
                     float* __restrict__ inv_deg) {
    const int NT = 1024, N = N_NODES;
    const int CH = (N + NT - 1) / NT;
    __shared__ int part[NT];
    int tid = threadIdx.x;
    int s0 = tid * CH;
    int s1 = s0 + CH; if (s1 > N) s1 = N;
    if (s0 > N) s0 = N;
    int s = 0;
    for (int i = s0; i < s1; ++i) s += cnt[i];
    part[tid] = s;
    __syncthreads();
    for (int off = 1; off < NT; off <<= 1) {
        int v = 0;
        if (tid >= off) v = part[tid - off];
        __syncthreads();
        if (tid >= off) part[tid] += v;
        __syncthreads();
    }
    int run = (tid == 0) ? 0 : part[tid - 1];
    for (int i = s0; i < s1; ++i) {
        row_ptr[i] = run;
        int c = cnt[i];
        inv_deg[i] = (c > 0) ? (1.0f / (float)c) : 0.0f;
        run += c;
    }
    if (tid == NT - 1) row_ptr[N] = run;
}

__global__ void scatter_kernel(const int* __restrict__ src, const int* __restrict__ dst,
                               const int* __restrict__ row_ptr, int* __restrict__ cursor,
                               int* __restrict__ csr_src, int nE) {
    int i = blockIdx.x * blockDim.x + threadIdx.x;
    if (i < nE) {
        int d = dst[i];
        int p = atomicAdd(&cursor[d], 1);
        csr_src[row_ptr[d] + p] = src[i];
    }
}

// ---------------------------------------------------------------------------
// f32 -> bf16 cast (vectorized)
// ---------------------------------------------------------------------------

__global__ void cast_kernel(const float4* __restrict__ in, ushort4* __restrict__ out, int n4) {
    int i = blockIdx.x * blockDim.x + threadIdx.x;
    if (i < n4) {
        float4 v = in[i];
        ushort4 o;
        o.x = f2b(v.x); o.y = f2b(v.y); o.z = f2b(v.z); o.w = f2b(v.w);
        out[i] = o;
    }
}

// ---------------------------------------------------------------------------
// Weight transpose + cast:  in f32 [K][N] row-major  ->  out bf16 [N][K]
// ---------------------------------------------------------------------------

__global__ __launch_bounds__(256)
void transpose_cast_kernel(const float* __restrict__ in, u16* __restrict__ out,
                           int K, int N) {
    __shared__ float t[32][33];
    int bx = blockIdx.x * 32;   // N direction
    int by = blockIdx.y * 32;   // K direction
    int x = threadIdx.x;        // 0..31
    int y = threadIdx.y;        // 0..7
#pragma unroll
    for (int i = 0; i < 32; i += 8) {
        int r = by + y + i, c = bx + x;
        if (r < K && c < N) t[y + i][x] = in[(size_t)r * N + c];
    }
    __syncthreads();
#pragma unroll
    for (int i = 0; i < 32; i += 8) {
        int r = bx + y + i, c = by + x;
        if (r < N && c < K) out[(size_t)r * K + c] = f2b(t[x][y + i]);
    }
}

// ---------------------------------------------------------------------------
// Mean aggregation over in-neighbors (bf16 in, f32 accumulate, bf16 out)
// ---------------------------------------------------------------------------

template<int D>
__global__ __launch_bounds__(256)
void aggregate_kernel(const u16* __restrict__ h, const int* __restrict__ row_ptr,
                      const int* __restrict__ csr_src, const float* __restrict__ inv_deg,
                      u16* __restrict__ out) {
    constexpr int C = (D + 255) / 256;
    int node = blockIdx.x;
    int tid = threadIdx.x;
    if (D < 256 && tid >= D) return;
    int e0 = row_ptr[node], e1 = row_ptr[node + 1];
    float acc[C];
#pragma unroll
    for (int c = 0; c < C; ++c) acc[c] = 0.0f;
    for (int e = e0; e < e1; ++e) {
        int s = csr_src[e];
        const u16* hp = h + (size_t)s * D;
#pragma unroll
        for (int c = 0; c < C; ++c) {
            int col = tid + c * 256;
            if (col < D) acc[c] += b2f(hp[col]);
        }
    }
    float wgt = inv_deg[node];
    u16* op = out + (size_t)node * D;
#pragma unroll
    for (int c = 0; c < C; ++c) {
        int col = tid + c * 256;
        if (col < D) op[col] = f2b(acc[c] * wgt);
    }
}

// ---------------------------------------------------------------------------
// MFMA GEMM (register-direct, no LDS):
//   C = [elu]( A0@W0 [+ A1@W1] [+ ADD] [+ bias] )
// A bf16 [M][K] row-major; W given pre-transposed bf16 [N][K]; ADD bf16 [M][N].
// Block 256 thr = 4 waves in 2x2; wave tile 64x64 (4x4 frags of 16x16x32).
// K % 32 == 0. M, N ragged (clamped loads, guarded stores).
// ---------------------------------------------------------------------------

template<bool DUAL, bool HASADD, bool FIN, bool OUTF32>
__global__ __launch_bounds__(256)
void mfma_gemm_kernel(const u16* __restrict__ A0, const u16* __restrict__ A1,
                      const u16* __restrict__ W0T, const u16* __restrict__ W1T,
                      const u16* __restrict__ ADD, const float* __restrict__ bias,
                      void* __restrict__ Cout, int M, int K, int N) {
    int tid = threadIdx.x;
    int wid = tid >> 6;
    int lane = tid & 63;
    int lr = lane & 15;        // row (A) / col (B) within fragment
    int lb = lane >> 4;        // k-block 0..3 (8 elems each)

    int bm = blockIdx.y * 128 + (wid >> 1) * 64;   // wave row base
    int bn = blockIdx.x * 128 + (wid & 1) * 64;    // wave col base

    float4v acc[4][4] = {};

    for (int s = 0; s < (DUAL ? 2 : 1); ++s) {
        const u16* Ap = (s == 0) ? A0 : A1;
        const u16* Wp = (s == 0) ? W0T : W1T;
        // clamped addresses (garbage rows/cols computed but never stored)
        size_t arow[4], bcol[4];
#pragma unroll
        for (int t = 0; t < 4; ++t) {
            int r = bm + t * 16 + lr; if (r > M - 1) r = M - 1;
            int c = bn + t * 16 + lr; if (c > N - 1) c = N - 1;
            arow[t] = (size_t)r * K;
            bcol[t] = (size_t)c * K;
        }
#pragma unroll 2
        for (int k0 = 0; k0 < K; k0 += 32) {
            short8v af[4], bf[4];
            int ko = k0 + lb * 8;
#pragma unroll
            for (int t = 0; t < 4; ++t)
                af[t] = *(const short8v*)(Ap + arow[t] + ko);
#pragma unroll
            for (int t = 0; t < 4; ++t)
                bf[t] = *(const short8v*)(Wp + bcol[t] + ko);
#pragma unroll
            for (int i = 0; i < 4; ++i)
#pragma unroll
                for (int j = 0; j < 4; ++j)
                    acc[i][j] = __builtin_amdgcn_mfma_f32_16x16x32_bf16(
                        af[i], bf[j], acc[i][j], 0, 0, 0);
        }
    }

    // epilogue: C[bm + i*16 + lb*4 + r][bn + j*16 + lr]
    float bi[4];
    if (FIN) {
#pragma unroll
        for (int j = 0; j < 4; ++j) {
            int c = bn + j * 16 + lr; if (c > N - 1) c = N - 1;
            bi[j] = bias[c];
        }
    }
#pragma unroll
    for (int i = 0; i < 4; ++i) {
#pragma unroll
        for (int r = 0; r < 4; ++r) {
            int row = bm + i * 16 + lb * 4 + r;
            if (row >= M) continue;
#pragma unroll
            for (int j = 0; j < 4; ++j) {
                int col = bn + j * 16 + lr;
                if (col >= N) continue;
                float v = acc[i][j][r];
                if (FIN) v += bi[j];
                if (HASADD) v += b2f(ADD[(size_t)row * N + col]);
                if (FIN) v = (v > 0.0f) ? v : expm1f(v);
                if (OUTF32) ((float*)Cout)[(size_t)row * N + col] = v;
                else        ((u16*)Cout)[(size_t)row * N + col] = f2b(v);
            }
        }
    }
}

// ---------------------------------------------------------------------------

extern "C" void kernel_launch(void* const* d_in, const int* in_sizes, int n_in,
                              void* d_out, int out_size, void* d_ws, size_t ws_size,
                              hipStream_t stream) {
    const float* features = (const float*)d_in[0];
    const int*   edge_src = (const int*)d_in[1];
    const int*   edge_dst = (const int*)d_in[2];
    const float* W1s = (const float*)d_in[3];
    const float* W1n = (const float*)d_in[4];
    const float* b1  = (const float*)d_in[5];
    const float* W2s = (const float*)d_in[6];
    const float* W2n = (const float*)d_in[7];
    const float* b2  = (const float*)d_in[8];
    const float* W3s = (const float*)d_in[9];
    const float* W3n = (const float*)d_in[10];
    const float* b3  = (const float*)d_in[11];
    const float* Wres = (const float*)d_in[12];
    const float* bres = (const float*)d_in[13];

    float* out_x   = (float*)d_out;
    float* out_res = out_x + (size_t)N_NODES * OUT_DIM;

    // ---- workspace layout ----
    size_t off = 0;
    auto carve = [&](size_t bytes) {
        size_t p = off;
        off += (bytes + 255) & ~(size_t)255;
        return p;
    };
    size_t o_cnt     = carve((size_t)N_NODES * 4);
    size_t o_rowptr  = carve((size_t)(N_NODES + 1) * 4);
    size_t o_cursor  = carve((size_t)N_NODES * 4);
    size_t o_invdeg  = carve((size_t)N_NODES * 4);
    size_t o_csr     = carve((size_t)N_EDGES * 4);
    // transposed bf16 weights
    size_t o_w1s = carve((size_t)IN_DIM * H1 * 2);
    size_t o_w1n = carve((size_t)IN_DIM * H1 * 2);
    size_t o_w2s = carve((size_t)H1 * H2 * 2);
    size_t o_w2n = carve((size_t)H1 * H2 * 2);
    size_t o_w3s = carve((size_t)H2 * OUT_DIM * 2);
    size_t o_w3n = carve((size_t)H2 * OUT_DIM * 2);
    size_t o_wrs = carve((size_t)IN_DIM * OUT_DIM * 2);
    // regionA: fX(25.6M)+aggF(25.6M); later x2(32M)
    size_t o_regA    = carve((size_t)N_NODES * (IN_DIM + IN_DIM) * 2);
    // regionB: x1(64M); later Y3+A3 (12.8M each)
    size_t o_regB    = carve((size_t)N_NODES * H1 * 2);
    size_t o_regC    = carve((size_t)N_NODES * H2 * 2);   // Y2
    size_t o_regD    = carve((size_t)N_NODES * H2 * 2);   // A2
    size_t REQUIRED  = off;
    if (ws_size < REQUIRED) return;   // diagnostic: stub-like failure => ws too small

    char* W = (char*)d_ws;
    int*   cnt     = (int*)(W + o_cnt);
    int*   row_ptr = (int*)(W + o_rowptr);
    int*   cursor  = (int*)(W + o_cursor);
    float* inv_deg = (float*)(W + o_invdeg);
    int*   csr_src = (int*)(W + o_csr);
    u16* W1sT = (u16*)(W + o_w1s);
    u16* W1nT = (u16*)(W + o_w1n);
    u16* W2sT = (u16*)(W + o_w2s);
    u16* W2nT = (u16*)(W + o_w2n);
    u16* W3sT = (u16*)(W + o_w3s);
    u16* W3nT = (u16*)(W + o_w3n);
    u16* WrsT = (u16*)(W + o_wrs);
    u16* fX   = (u16*)(W + o_regA);
    u16* aggF = fX + (size_t)N_NODES * IN_DIM;
    u16* x2   = (u16*)(W + o_regA);            // aliases fX+aggF (dead by then)
    u16* x1   = (u16*)(W + o_regB);
    u16* Y3   = (u16*)(W + o_regB);            // aliases x1 (dead by then)
    u16* A3   = Y3 + (size_t)N_NODES * OUT_DIM;
    u16* Y2   = (u16*)(W + o_regC);
    u16* A2   = (u16*)(W + o_regD);

    const int mt = (N_NODES + 127) / 128;      // 391 M-tiles

    // ---- CSR build ----
    zero2_kernel<<<(N_NODES + 255) / 256, 256, 0, stream>>>(cnt, cursor, N_NODES);
    count_deg_kernel<<<(N_EDGES + 255) / 256, 256, 0, stream>>>(edge_dst, cnt, N_EDGES);
    scan_deg_kernel<<<1, 1024, 0, stream>>>(cnt, row_ptr, inv_deg);
    scatter_kernel<<<(N_EDGES + 255) / 256, 256, 0, stream>>>(edge_src, edge_dst, row_ptr,
                                                              cursor, csr_src, N_EDGES);

    // ---- casts ----
    {
        int n4 = N_NODES * IN_DIM / 4;
        cast_kernel<<<(n4 + 255) / 256, 256, 0, stream>>>((const float4*)features,
                                                          (ushort4*)fX, n4);
    }
    {
        dim3 b(32, 8);
        dim3 g1(H1 / 32, IN_DIM / 32);
        transpose_cast_kernel<<<g1, b, 0, stream>>>(W1s, W1sT, IN_DIM, H1);
        transpose_cast_kernel<<<g1, b, 0, stream>>>(W1n, W1nT, IN_DIM, H1);
        dim3 g2(H2 / 32, H1 / 32);
        transpose_cast_kernel<<<g2, b, 0, stream>>>(W2s, W2sT, H1, H2);
        transpose_cast_kernel<<<g2, b, 0, stream>>>(W2n, W2nT, H1, H2);
        dim3 g3(OUT_DIM / 32, H2 / 32);
        transpose_cast_kernel<<<g3, b, 0, stream>>>(W3s, W3sT, H2, OUT_DIM);
        transpose_cast_kernel<<<g3, b, 0, stream>>>(W3n, W3nT, H2, OUT_DIM);
        dim3 g4(OUT_DIM / 32, IN_DIM / 32);
        transpose_cast_kernel<<<g4, b, 0, stream>>>(Wres, WrsT, IN_DIM, OUT_DIM);
    }

    // ---- residual head: out_res = elu(fX@Wres + bres)  (f32 out) ----
    mfma_gemm_kernel<false, false, true, true><<<dim3(1, mt), 256, 0, stream>>>(
        fX, nullptr, WrsT, nullptr, nullptr, bres, out_res, N_NODES, IN_DIM, OUT_DIM);

    // ---- layer 1 (aggregate-before; dual GEMM) ----
    aggregate_kernel<IN_DIM><<<N_NODES, 256, 0, stream>>>(fX, row_ptr, csr_src, inv_deg, aggF);
    mfma_gemm_kernel<true, false, true, false><<<dim3(H1 / 128, mt), 256, 0, stream>>>(
        fX, aggF, W1sT, W1nT, nullptr, b1, x1, N_NODES, IN_DIM, H1);

    // ---- layer 2 (aggregate-after: x2 = elu(x1@W2s + S(x1@W2n) + b2)) ----
    mfma_gemm_kernel<false, false, false, false><<<dim3((H2 + 127) / 128, mt), 256, 0, stream>>>(
        x1, nullptr, W2nT, nullptr, nullptr, nullptr, Y2, N_NODES, H1, H2);
    aggregate_kernel<H2><<<N_NODES, 256, 0, stream>>>(Y2, row_ptr, csr_src, inv_deg, A2);
    mfma_gemm_kernel<false, true, true, false><<<dim3((H2 + 127) / 128, mt), 256, 0, stream>>>(
        x1, nullptr, W2sT, nullptr, A2, b2, x2, N_NODES, H1, H2);

    // ---- layer 3 (aggregate-after) ----
    mfma_gemm_kernel<false, false, false, false><<<dim3(1, mt), 256, 0, stream>>>(
        x2, nullptr, W3nT, nullptr, nullptr, nullptr, Y3, N_NODES, H2, OUT_DIM);
    aggregate_kernel<OUT_DIM><<<N_NODES, 256, 0, stream>>>(Y3, row_ptr, csr_src, inv_deg, A3);
    mfma_gemm_kernel<false, true, true, true><<<dim3(1, mt), 256, 0, stream>>>(
        x2, nullptr, W3sT, nullptr, A3, b3, out_x, N_NODES, H2, OUT_DIM);
}

// Round 4
// 897.739 us; speedup vs baseline: 2.1341x; 1.2943x over previous
//
#include <hip/hip_runtime.h>
#include <hip/hip_bf16.h>
#include <cstdint>
#include <cstddef>

#define N_NODES 50000
#define N_EDGES 800000
#define IN_DIM 256
#define H1 640
#define H2 320
#define OUT_DIM 128

typedef unsigned short u16;
typedef __attribute__((ext_vector_type(8))) short short8v;   // 8 bf16 = 4 VGPR
typedef __attribute__((ext_vector_type(4))) float float4v;   // MFMA C/D

__device__ __forceinline__ float b2f(u16 u) {
    union { unsigned int i; float f; } v; v.i = ((unsigned int)u) << 16; return v.f;
}
__device__ __forceinline__ u16 f2b(float f) {
    __hip_bfloat16 h = __float2bfloat16(f);
    return *reinterpret_cast<u16*>(&h);
}

// ---------------------------------------------------------------------------
// CSR build
// ---------------------------------------------------------------------------

__global__ void zero2_kernel(int* __restrict__ a, int* __restrict__ b, int n) {
    int i = blockIdx.x * blockDim.x + threadIdx.x;
    if (i < n) { a[i] = 0; b[i] = 0; }
}

__global__ void count_deg_kernel(const int* __restrict__ dst, int* __restrict__ cnt, int nE) {
    int i = blockIdx.x * blockDim.x + threadIdx.x;
    if (i < nE) atomicAdd(&cnt[dst[i]], 1);
}

__global__ __launch_bounds__(1024)
void scan_deg_kernel(const int* __restrict__ cnt, int* __restrict__ row_ptr,
                     float* __restrict__ inv_deg) {
    const int NT = 1024, N = N_NODES;
    const int CH = (N + NT - 1) / NT;
    __shared__ int part[NT];
    int tid = threadIdx.x;
    int s0 = tid * CH;
    int s1 = s0 + CH; if (s1 > N) s1 = N;
    if (s0 > N) s0 = N;
    int s = 0;
    for (int i = s0; i < s1; ++i) s += cnt[i];
    part[tid] = s;
    __syncthreads();
    for (int off = 1; off < NT; off <<= 1) {
        int v = 0;
        if (tid >= off) v = part[tid - off];
        __syncthreads();
        if (tid >= off) part[tid] += v;
        __syncthreads();
    }
    int run = (tid == 0) ? 0 : part[tid - 1];
    for (int i = s0; i < s1; ++i) {
        row_ptr[i] = run;
        int c = cnt[i];
        inv_deg[i] = (c > 0) ? (1.0f / (float)c) : 0.0f;
        run += c;
    }
    if (tid == NT - 1) row_ptr[N] = run;
}

__global__ void scatter_kernel(const int* __restrict__ src, const int* __restrict__ dst,
                               const int* __restrict__ row_ptr, int* __restrict__ cursor,
                               int* __restrict__ csr_src, int nE) {
    int i = blockIdx.x * blockDim.x + threadIdx.x;
    if (i < nE) {
        int d = dst[i];
        int p = atomicAdd(&cursor[d], 1);
        csr_src[row_ptr[d] + p] = src[i];
    }
}

// ---------------------------------------------------------------------------
// f32 -> bf16 cast (vectorized)
// ---------------------------------------------------------------------------

__global__ void cast_kernel(const float4* __restrict__ in, ushort4* __restrict__ out, int n4) {
    int i = blockIdx.x * blockDim.x + threadIdx.x;
    if (i < n4) {
        float4 v = in[i];
        ushort4 o;
        o.x = f2b(v.x); o.y = f2b(v.y); o.z = f2b(v.z); o.w = f2b(v.w);
        out[i] = o;
    }
}

// ---------------------------------------------------------------------------
// Weight transpose + cast:  in f32 [K][N] row-major  ->  out bf16 [N][K]
// ---------------------------------------------------------------------------

__global__ __launch_bounds__(256)
void transpose_cast_kernel(const float* __restrict__ in, u16* __restrict__ out,
                           int K, int N) {
    __shared__ float t[32][33];
    int bx = blockIdx.x * 32;   // N direction
    int by = blockIdx.y * 32;   // K direction
    int x = threadIdx.x;        // 0..31
    int y = threadIdx.y;        // 0..7
#pragma unroll
    for (int i = 0; i < 32; i += 8) {
        int r = by + y + i, c = bx + x;
        if (r < K && c < N) t[y + i][x] = in[(size_t)r * N + c];
    }
    __syncthreads();
#pragma unroll
    for (int i = 0; i < 32; i += 8) {
        int r = bx + y + i, c = by + x;
        if (r < N && c < K) out[(size_t)r * K + c] = f2b(t[x][y + i]);
    }
}

// ---------------------------------------------------------------------------
// Mean aggregation over in-neighbors (bf16 in, f32 accumulate, bf16 out).
// One block (256 threads) per node, but edge-parallel inside the block:
//   cg = t % (D/8)  -> which 8-col group this thread loads (16 B vector)
//   es = t / (D/8)  -> which edge slot; NES edges in flight concurrently
// Cross-slot reduce via LDS [8][256] (conflict-free), then scale+store.
// ---------------------------------------------------------------------------

template<int D>
__global__ __launch_bounds__(256)
void aggregate_kernel(const u16* __restrict__ h, const int* __restrict__ row_ptr,
                      const int* __restrict__ csr_src, const float* __restrict__ inv_deg,
                      u16* __restrict__ out) {
    constexpr int NCG = D / 8;           // col groups (16B each)
    constexpr int NES = 256 / NCG;       // edge slots in flight
    constexpr int ACT = NCG * NES;       // active threads
    __shared__ float red[8][256];
    int node = blockIdx.x;
    int t = threadIdx.x;
    int cg = t % NCG;
    int es = t / NCG;
    int e0 = row_ptr[node], e1 = row_ptr[node + 1];

    float acc[8];
#pragma unroll
    for (int j = 0; j < 8; ++j) acc[j] = 0.0f;

    if (t < ACT) {
        const u16* __restrict__ hb = h + cg * 8;
        int e = e0 + es;
        int sNext = (e < e1) ? csr_src[e] : 0;
        while (e < e1) {
            int s = sNext;
            int e2 = e + NES;
            sNext = (e2 < e1) ? csr_src[e2] : 0;   // prefetch next index
            short8v v = *(const short8v*)(hb + (size_t)s * D);
#pragma unroll
            for (int j = 0; j < 8; ++j) acc[j] += b2f((u16)v[j]);
            e = e2;
        }
    }
#pragma unroll
    for (int j = 0; j < 8; ++j) red[j][t] = acc[j];
    __syncthreads();

    if (t < NCG) {
        float sum[8];
#pragma unroll
        for (int j = 0; j < 8; ++j) sum[j] = red[j][t];
#pragma unroll
        for (int s2 = 1; s2 < NES; ++s2) {
#pragma unroll
            for (int j = 0; j < 8; ++j) sum[j] += red[j][s2 * NCG + t];
        }
        float w = inv_deg[node];
        short8v o;
#pragma unroll
        for (int j = 0; j < 8; ++j) o[j] = (short)f2b(sum[j] * w);
        *(short8v*)(out + (size_t)node * D + t * 8) = o;
    }
}

// ---------------------------------------------------------------------------
// MFMA GEMM (register-direct, no LDS):
//   C = [elu]( A0@W0 [+ A1@W1] [+ ADD] [+ bias] )
// A bf16 [M][K] row-major; W pre-transposed bf16 [N][K]; ADD bf16 [M][N].
// Block 256 thr = 4 waves in 2x2; wave tile 64x64 (4x4 frags of 16x16x32).
// ---------------------------------------------------------------------------

template<bool DUAL, bool HASADD, bool FIN, bool OUTF32>
__global__ __launch_bounds__(256)
void mfma_gemm_kernel(const u16* __restrict__ A0, const u16* __restrict__ A1,
                      const u16* __restrict__ W0T, const u16* __restrict__ W1T,
                      const u16* __restrict__ ADD, const float* __restrict__ bias,
                      void* __restrict__ Cout, int M, int K, int N) {
    int tid = threadIdx.x;
    int wid = tid >> 6;
    int lane = tid & 63;
    int lr = lane & 15;        // row (A) / col (B) within fragment
    int lb = lane >> 4;        // k-block 0..3 (8 elems each)

    int bm = blockIdx.y * 128 + (wid >> 1) * 64;   // wave row base
    int bn = blockIdx.x * 128 + (wid & 1) * 64;    // wave col base

    float4v acc[4][4] = {};

    for (int s = 0; s < (DUAL ? 2 : 1); ++s) {
        const u16* Ap = (s == 0) ? A0 : A1;
        const u16* Wp = (s == 0) ? W0T : W1T;
        size_t arow[4], bcol[4];
#pragma unroll
        for (int t = 0; t < 4; ++t) {
            int r = bm + t * 16 + lr; if (r > M - 1) r = M - 1;
            int c = bn + t * 16 + lr; if (c > N - 1) c = N - 1;
            arow[t] = (size_t)r * K;
            bcol[t] = (size_t)c * K;
        }
#pragma unroll 2
        for (int k0 = 0; k0 < K; k0 += 32) {
            short8v af[4], bf[4];
            int ko = k0 + lb * 8;
#pragma unroll
            for (int t = 0; t < 4; ++t)
                af[t] = *(const short8v*)(Ap + arow[t] + ko);
#pragma unroll
            for (int t = 0; t < 4; ++t)
                bf[t] = *(const short8v*)(Wp + bcol[t] + ko);
#pragma unroll
            for (int i = 0; i < 4; ++i)
#pragma unroll
                for (int j = 0; j < 4; ++j)
                    acc[i][j] = __builtin_amdgcn_mfma_f32_16x16x32_bf16(
                        af[i], bf[j], acc[i][j], 0, 0, 0);
        }
    }

    float bi[4];
    if (FIN) {
#pragma unroll
        for (int j = 0; j < 4; ++j) {
            int c = bn + j * 16 + lr; if (c > N - 1) c = N - 1;
            bi[j] = bias[c];
        }
    }
#pragma unroll
    for (int i = 0; i < 4; ++i) {
#pragma unroll
        for (int r = 0; r < 4; ++r) {
            int row = bm + i * 16 + lb * 4 + r;
            if (row >= M) continue;
#pragma unroll
            for (int j = 0; j < 4; ++j) {
                int col = bn + j * 16 + lr;
                if (col >= N) continue;
                float v = acc[i][j][r];
                if (FIN) v += bi[j];
                if (HASADD) v += b2f(ADD[(size_t)row * N + col]);
                if (FIN) v = (v > 0.0f) ? v : expm1f(v);
                if (OUTF32) ((float*)Cout)[(size_t)row * N + col] = v;
                else        ((u16*)Cout)[(size_t)row * N + col] = f2b(v);
            }
        }
    }
}

// ---------------------------------------------------------------------------

extern "C" void kernel_launch(void* const* d_in, const int* in_sizes, int n_in,
                              void* d_out, int out_size, void* d_ws, size_t ws_size,
                              hipStream_t stream) {
    const float* features = (const float*)d_in[0];
    const int*   edge_src = (const int*)d_in[1];
    const int*   edge_dst = (const int*)d_in[2];
    const float* W1s = (const float*)d_in[3];
    const float* W1n = (const float*)d_in[4];
    const float* b1  = (const float*)d_in[5];
    const float* W2s = (const float*)d_in[6];
    const float* W2n = (const float*)d_in[7];
    const float* b2  = (const float*)d_in[8];
    const float* W3s = (const float*)d_in[9];
    const float* W3n = (const float*)d_in[10];
    const float* b3  = (const float*)d_in[11];
    const float* Wres = (const float*)d_in[12];
    const float* bres = (const float*)d_in[13];

    float* out_x   = (float*)d_out;
    float* out_res = out_x + (size_t)N_NODES * OUT_DIM;

    // ---- workspace layout ----
    size_t off = 0;
    auto carve = [&](size_t bytes) {
        size_t p = off;
        off += (bytes + 255) & ~(size_t)255;
        return p;
    };
    size_t o_cnt     = carve((size_t)N_NODES * 4);
    size_t o_rowptr  = carve((size_t)(N_NODES + 1) * 4);
    size_t o_cursor  = carve((size_t)N_NODES * 4);
    size_t o_invdeg  = carve((size_t)N_NODES * 4);
    size_t o_csr     = carve((size_t)N_EDGES * 4);
    size_t o_w1s = carve((size_t)IN_DIM * H1 * 2);
    size_t o_w1n = carve((size_t)IN_DIM * H1 * 2);
    size_t o_w2s = carve((size_t)H1 * H2 * 2);
    size_t o_w2n = carve((size_t)H1 * H2 * 2);
    size_t o_w3s = carve((size_t)H2 * OUT_DIM * 2);
    size_t o_w3n = carve((size_t)H2 * OUT_DIM * 2);
    size_t o_wrs = carve((size_t)IN_DIM * OUT_DIM * 2);
    size_t o_regA    = carve((size_t)N_NODES * (IN_DIM + IN_DIM) * 2);  // fX+aggF / x2
    size_t o_regB    = carve((size_t)N_NODES * H1 * 2);                 // x1 / Y3+A3
    size_t o_regC    = carve((size_t)N_NODES * H2 * 2);                 // Y2
    size_t o_regD    = carve((size_t)N_NODES * H2 * 2);                 // A2
    size_t REQUIRED  = off;
    if (ws_size < REQUIRED) return;

    char* W = (char*)d_ws;
    int*   cnt     = (int*)(W + o_cnt);
    int*   row_ptr = (int*)(W + o_rowptr);
    int*   cursor  = (int*)(W + o_cursor);
    float* inv_deg = (float*)(W + o_invdeg);
    int*   csr_src = (int*)(W + o_csr);
    u16* W1sT = (u16*)(W + o_w1s);
    u16* W1nT = (u16*)(W + o_w1n);
    u16* W2sT = (u16*)(W + o_w2s);
    u16* W2nT = (u16*)(W + o_w2n);
    u16* W3sT = (u16*)(W + o_w3s);
    u16* W3nT = (u16*)(W + o_w3n);
    u16* WrsT = (u16*)(W + o_wrs);
    u16* fX   = (u16*)(W + o_regA);
    u16* aggF = fX + (size_t)N_NODES * IN_DIM;
    u16* x2   = (u16*)(W + o_regA);            // aliases fX+aggF (dead by then)
    u16* x1   = (u16*)(W + o_regB);
    u16* Y3   = (u16*)(W + o_regB);            // aliases x1 (dead by then)
    u16* A3   = Y3 + (size_t)N_NODES * OUT_DIM;
    u16* Y2   = (u16*)(W + o_regC);
    u16* A2   = (u16*)(W + o_regD);

    const int mt = (N_NODES + 127) / 128;

    // ---- CSR build ----
    zero2_kernel<<<(N_NODES + 255) / 256, 256, 0, stream>>>(cnt, cursor, N_NODES);
    count_deg_kernel<<<(N_EDGES + 255) / 256, 256, 0, stream>>>(edge_dst, cnt, N_EDGES);
    scan_deg_kernel<<<1, 1024, 0, stream>>>(cnt, row_ptr, inv_deg);
    scatter_kernel<<<(N_EDGES + 255) / 256, 256, 0, stream>>>(edge_src, edge_dst, row_ptr,
                                                              cursor, csr_src, N_EDGES);

    // ---- casts ----
    {
        int n4 = N_NODES * IN_DIM / 4;
        cast_kernel<<<(n4 + 255) / 256, 256, 0, stream>>>((const float4*)features,
                                                          (ushort4*)fX, n4);
    }
    {
        dim3 b(32, 8);
        dim3 g1(H1 / 32, IN_DIM / 32);
        transpose_cast_kernel<<<g1, b, 0, stream>>>(W1s, W1sT, IN_DIM, H1);
        transpose_cast_kernel<<<g1, b, 0, stream>>>(W1n, W1nT, IN_DIM, H1);
        dim3 g2(H2 / 32, H1 / 32);
        transpose_cast_kernel<<<g2, b, 0, stream>>>(W2s, W2sT, H1, H2);
        transpose_cast_kernel<<<g2, b, 0, stream>>>(W2n, W2nT, H1, H2);
        dim3 g3(OUT_DIM / 32, H2 / 32);
        transpose_cast_kernel<<<g3, b, 0, stream>>>(W3s, W3sT, H2, OUT_DIM);
        transpose_cast_kernel<<<g3, b, 0, stream>>>(W3n, W3nT, H2, OUT_DIM);
        dim3 g4(OUT_DIM / 32, IN_DIM / 32);
        transpose_cast_kernel<<<g4, b, 0, stream>>>(Wres, WrsT, IN_DIM, OUT_DIM);
    }

    // ---- residual head ----
    mfma_gemm_kernel<false, false, true, true><<<dim3(1, mt), 256, 0, stream>>>(
        fX, nullptr, WrsT, nullptr, nullptr, bres, out_res, N_NODES, IN_DIM, OUT_DIM);

    // ---- layer 1 (aggregate-before; dual GEMM) ----
    aggregate_kernel<IN_DIM><<<N_NODES, 256, 0, stream>>>(fX, row_ptr, csr_src, inv_deg, aggF);
    mfma_gemm_kernel<true, false, true, false><<<dim3(H1 / 128, mt), 256, 0, stream>>>(
        fX, aggF, W1sT, W1nT, nullptr, b1, x1, N_NODES, IN_DIM, H1);

    // ---- layer 2 (aggregate-after) ----
    mfma_gemm_kernel<false, false, false, false><<<dim3((H2 + 127) / 128, mt), 256, 0, stream>>>(
        x1, nullptr, W2nT, nullptr, nullptr, nullptr, Y2, N_NODES, H1, H2);
    aggregate_kernel<H2><<<N_NODES, 256, 0, stream>>>(Y2, row_ptr, csr_src, inv_deg, A2);
    mfma_gemm_kernel<false, true, true, false><<<dim3((H2 + 127) / 128, mt), 256, 0, stream>>>(
        x1, nullptr, W2sT, nullptr, A2, b2, x2, N_NODES, H1, H2);

    // ---- layer 3 (aggregate-after) ----
    mfma_gemm_kernel<false, false, false, false><<<dim3(1, mt), 256, 0, stream>>>(
        x2, nullptr, W3nT, nullptr, nullptr, nullptr, Y3, N_NODES, H2, OUT_DIM);
    aggregate_kernel<OUT_DIM><<<N_NODES, 256, 0, stream>>>(Y3, row_ptr, csr_src, inv_deg, A3);
    mfma_gemm_kernel<false, true, true, true><<<dim3(1, mt), 256, 0, stream>>>(
        x2, nullptr, W3sT, nullptr, A3, b3, out_x, N_NODES, H2, OUT_DIM);
}

// Round 5
// 865.740 us; speedup vs baseline: 2.2129x; 1.0370x over previous
//
#include <hip/hip_runtime.h>
#include <hip/hip_bf16.h>
#include <cstdint>
#include <cstddef>

#define N_NODES 50000
#define N_EDGES 800000
#define IN_DIM 256
#define H1 640
#define H2 320
#define OUT_DIM 128

typedef unsigned short u16;
typedef __attribute__((ext_vector_type(8))) short short8v;   // 8 bf16 = 4 VGPR
typedef __attribute__((ext_vector_type(4))) float float4v;   // MFMA C/D

__device__ __forceinline__ float b2f(u16 u) {
    union { unsigned int i; float f; } v; v.i = ((unsigned int)u) << 16; return v.f;
}
__device__ __forceinline__ u16 f2b(float f) {
    __hip_bfloat16 h = __float2bfloat16(f);
    return *reinterpret_cast<u16*>(&h);
}

// ---------------------------------------------------------------------------
// CSR build
// ---------------------------------------------------------------------------

__global__ void zero2_kernel(int* __restrict__ a, int* __restrict__ b, int n) {
    int i = blockIdx.x * blockDim.x + threadIdx.x;
    if (i < n) { a[i] = 0; b[i] = 0; }
}

__global__ void count_deg_kernel(const int* __restrict__ dst, int* __restrict__ cnt, int nE) {
    int i = blockIdx.x * blockDim.x + threadIdx.x;
    if (i < nE) atomicAdd(&cnt[dst[i]], 1);
}

__global__ __launch_bounds__(1024)
void scan_deg_kernel(const int* __restrict__ cnt, int* __restrict__ row_ptr,
                     float* __restrict__ inv_deg) {
    const int NT = 1024, N = N_NODES;
    const int CH = (N + NT - 1) / NT;
    __shared__ int part[NT];
    int tid = threadIdx.x;
    int s0 = tid * CH;
    int s1 = s0 + CH; if (s1 > N) s1 = N;
    if (s0 > N) s0 = N;
    int s = 0;
    for (int i = s0; i < s1; ++i) s += cnt[i];
    part[tid] = s;
    __syncthreads();
    for (int off = 1; off < NT; off <<= 1) {
        int v = 0;
        if (tid >= off) v = part[tid - off];
        __syncthreads();
        if (tid >= off) part[tid] += v;
        __syncthreads();
    }
    int run = (tid == 0) ? 0 : part[tid - 1];
    for (int i = s0; i < s1; ++i) {
        row_ptr[i] = run;
        int c = cnt[i];
        inv_deg[i] = (c > 0) ? (1.0f / (float)c) : 0.0f;
        run += c;
    }
    if (tid == NT - 1) row_ptr[N] = run;
}

__global__ void scatter_kernel(const int* __restrict__ src, const int* __restrict__ dst,
                               const int* __restrict__ row_ptr, int* __restrict__ cursor,
                               int* __restrict__ csr_src, int nE) {
    int i = blockIdx.x * blockDim.x + threadIdx.x;
    if (i < nE) {
        int d = dst[i];
        int p = atomicAdd(&cursor[d], 1);
        csr_src[row_ptr[d] + p] = src[i];
    }
}

// ---------------------------------------------------------------------------
// f32 -> bf16 cast (vectorized)
// ---------------------------------------------------------------------------

__global__ void cast_kernel(const float4* __restrict__ in, ushort4* __restrict__ out, int n4) {
    int i = blockIdx.x * blockDim.x + threadIdx.x;
    if (i < n4) {
        float4 v = in[i];
        ushort4 o;
        o.x = f2b(v.x); o.y = f2b(v.y); o.z = f2b(v.z); o.w = f2b(v.w);
        out[i] = o;
    }
}

// ---------------------------------------------------------------------------
// Weight transpose + cast:  in f32 [K][N] row-major  ->  out bf16 [N][K]
// ---------------------------------------------------------------------------

__global__ __launch_bounds__(256)
void transpose_cast_kernel(const float* __restrict__ in, u16* __restrict__ out,
                           int K, int N) {
    __shared__ float t[32][33];
    int bx = blockIdx.x * 32;   // N direction
    int by = blockIdx.y * 32;   // K direction
    int x = threadIdx.x;        // 0..31
    int y = threadIdx.y;        // 0..7
#pragma unroll
    for (int i = 0; i < 32; i += 8) {
        int r = by + y + i, c = bx + x;
        if (r < K && c < N) t[y + i][x] = in[(size_t)r * N + c];
    }
    __syncthreads();
#pragma unroll
    for (int i = 0; i < 32; i += 8) {
        int r = bx + y + i, c = by + x;
        if (r < N && c < K) out[(size_t)r * K + c] = f2b(t[x][y + i]);
    }
}

// ---------------------------------------------------------------------------
// Mean aggregation over in-neighbors, edge-parallel per block.
//   cg = t % (D/8) -> 8-col group (16 B vector); es = t / (D/8) -> edge slot
// MODE 0: out_bf16 = sum * w                        (T, bias unused)
// MODE 1: out_bf16 = elu(sum*w + T_bf16 + bias)
// MODE 2: out_f32  = elu(sum*w + T_f32  + bias)
// ---------------------------------------------------------------------------

template<int D, int MODE>
__global__ __launch_bounds__(256)
void aggregate_kernel(const u16* __restrict__ h, const int* __restrict__ row_ptr,
                      const int* __restrict__ csr_src, const float* __restrict__ inv_deg,
                      const void* __restrict__ T, const float* __restrict__ bias,
                      void* __restrict__ out) {
    constexpr int NCG = D / 8;           // col groups (16B each)
    constexpr int NES = 256 / NCG;       // edge slots in flight
    constexpr int ACT = NCG * NES;       // active threads
    __shared__ float red[8][256];
    int node = blockIdx.x;
    int t = threadIdx.x;
    int cg = t % NCG;
    int es = t / NCG;
    int e0 = row_ptr[node], e1 = row_ptr[node + 1];

    float acc[8];
#pragma unroll
    for (int j = 0; j < 8; ++j) acc[j] = 0.0f;

    if (t < ACT) {
        const u16* __restrict__ hb = h + cg * 8;
        int e = e0 + es;
        int sNext = (e < e1) ? csr_src[e] : 0;
        while (e < e1) {
            int s = sNext;
            int e2 = e + NES;
            sNext = (e2 < e1) ? csr_src[e2] : 0;   // prefetch next index
            short8v v = *(const short8v*)(hb + (size_t)s * D);
#pragma unroll
            for (int j = 0; j < 8; ++j) acc[j] += b2f((u16)v[j]);
            e = e2;
        }
    }
#pragma unroll
    for (int j = 0; j < 8; ++j) red[j][t] = acc[j];
    __syncthreads();

    if (t < NCG) {
        float sum[8];
#pragma unroll
        for (int j = 0; j < 8; ++j) sum[j] = red[j][t];
#pragma unroll
        for (int s2 = 1; s2 < NES; ++s2) {
#pragma unroll
            for (int j = 0; j < 8; ++j) sum[j] += red[j][s2 * NCG + t];
        }
        float w = inv_deg[node];
        if (MODE == 0) {
            short8v o;
#pragma unroll
            for (int j = 0; j < 8; ++j) o[j] = (short)f2b(sum[j] * w);
            *(short8v*)((u16*)out + (size_t)node * D + t * 8) = o;
        } else {
            float tv[8];
            if (MODE == 1) {
                short8v tb = *(const short8v*)((const u16*)T + (size_t)node * D + t * 8);
#pragma unroll
                for (int j = 0; j < 8; ++j) tv[j] = b2f((u16)tb[j]);
            } else {
                const float* tp = (const float*)T + (size_t)node * D + t * 8;
                float4 a = *(const float4*)tp, b = *(const float4*)(tp + 4);
                tv[0] = a.x; tv[1] = a.y; tv[2] = a.z; tv[3] = a.w;
                tv[4] = b.x; tv[5] = b.y; tv[6] = b.z; tv[7] = b.w;
            }
            const float* bp = bias + t * 8;
            float4 ba = *(const float4*)bp, bb = *(const float4*)(bp + 4);
            float bv[8] = {ba.x, ba.y, ba.z, ba.w, bb.x, bb.y, bb.z, bb.w};
            float v[8];
#pragma unroll
            for (int j = 0; j < 8; ++j) {
                float x = sum[j] * w + tv[j] + bv[j];
                v[j] = (x > 0.0f) ? x : expm1f(x);
            }
            if (MODE == 1) {
                short8v o;
#pragma unroll
                for (int j = 0; j < 8; ++j) o[j] = (short)f2b(v[j]);
                *(short8v*)((u16*)out + (size_t)node * D + t * 8) = o;
            } else {
                float* op = (float*)out + (size_t)node * D + t * 8;
                *(float4*)op = make_float4(v[0], v[1], v[2], v[3]);
                *(float4*)(op + 4) = make_float4(v[4], v[5], v[6], v[7]);
            }
        }
    }
}

// ---------------------------------------------------------------------------
// MFMA GEMM (register-direct, no LDS), 1D grid with bijective XCD swizzle.
//   acc = A0@W0T' [+ A1@W1T']     (W given pre-transposed bf16 [N][K])
// EPI 0: C0 bf16 = elu(acc + bias)        (single output)
// EPI 1: C0 f32  = elu(acc + bias)
// EPI 2: split at N0: C0 bf16 raw | C1 bf16 raw
// EPI 3: split at N0: C0 bf16 raw | C1 f32 raw
// Block 256 thr = 4 waves 2x2; wave tile 64x64 (4x4 frags of 16x16x32).
// ---------------------------------------------------------------------------

template<bool DUAL, int EPI>
__global__ __launch_bounds__(256)
void mfma_gemm_kernel(const u16* __restrict__ A0, const u16* __restrict__ A1,
                      const u16* __restrict__ W0T, const u16* __restrict__ W1T,
                      const float* __restrict__ bias,
                      void* __restrict__ C0, void* __restrict__ C1,
                      int M, int K, int N, int N0, int gx) {
    // bijective XCD swizzle (m204): hw assigns block d to XCD d%8; give each
    // XCD a contiguous chunk of the flat tile space -> same-M-tile N-tiles
    // share one XCD's L2.
    int nwg = gridDim.x;
    int d = blockIdx.x;
    int q = nwg >> 3, r = nwg & 7;
    int xcd = d & 7, idx = d >> 3;
    int flat = (xcd < r ? xcd * (q + 1) : r * (q + 1) + (xcd - r) * q) + idx;
    int bxt = flat % gx, byt = flat / gx;

    int tid = threadIdx.x;
    int wid = tid >> 6;
    int lane = tid & 63;
    int lr = lane & 15;        // row (A) / col (B) within fragment
    int lb = lane >> 4;        // k-block 0..3 (8 elems each)

    int bm = byt * 128 + (wid >> 1) * 64;
    int bn = bxt * 128 + (wid & 1) * 64;

    float4v acc[4][4] = {};

    for (int s = 0; s < (DUAL ? 2 : 1); ++s) {
        const u16* Ap = (s == 0) ? A0 : A1;
        const u16* Wp = (s == 0) ? W0T : W1T;
        size_t arow[4], bcol[4];
#pragma unroll
        for (int t = 0; t < 4; ++t) {
            int rr = bm + t * 16 + lr; if (rr > M - 1) rr = M - 1;
            int cc = bn + t * 16 + lr; if (cc > N - 1) cc = N - 1;
            arow[t] = (size_t)rr * K;
            bcol[t] = (size_t)cc * K;
        }
#pragma unroll 2
        for (int k0 = 0; k0 < K; k0 += 32) {
            short8v af[4], bf[4];
            int ko = k0 + lb * 8;
#pragma unroll
            for (int t = 0; t < 4; ++t)
                af[t] = *(const short8v*)(Ap + arow[t] + ko);
#pragma unroll
            for (int t = 0; t < 4; ++t)
                bf[t] = *(const short8v*)(Wp + bcol[t] + ko);
#pragma unroll
            for (int i = 0; i < 4; ++i)
#pragma unroll
                for (int j = 0; j < 4; ++j)
                    acc[i][j] = __builtin_amdgcn_mfma_f32_16x16x32_bf16(
                        af[i], bf[j], acc[i][j], 0, 0, 0);
        }
    }

    // epilogue: C[bm + i*16 + lb*4 + rr][bn + j*16 + lr]
    if (EPI <= 1) {
        float bi[4];
#pragma unroll
        for (int j = 0; j < 4; ++j) {
            int c = bn + j * 16 + lr; if (c > N - 1) c = N - 1;
            bi[j] = bias[c];
        }
#pragma unroll
        for (int i = 0; i < 4; ++i) {
#pragma unroll
            for (int rr = 0; rr < 4; ++rr) {
                int row = bm + i * 16 + lb * 4 + rr;
                if (row >= M) continue;
#pragma unroll
                for (int j = 0; j < 4; ++j) {
                    int col = bn + j * 16 + lr;
                    float v = acc[i][j][rr] + bi[j];
                    v = (v > 0.0f) ? v : expm1f(v);
                    if (EPI == 1) ((float*)C0)[(size_t)row * N + col] = v;
                    else          ((u16*)C0)[(size_t)row * N + col] = f2b(v);
                }
            }
        }
    } else {
        int N1 = N - N0;
#pragma unroll
        for (int i = 0; i < 4; ++i) {
#pragma unroll
            for (int rr = 0; rr < 4; ++rr) {
                int row = bm + i * 16 + lb * 4 + rr;
                if (row >= M) continue;
#pragma unroll
                for (int j = 0; j < 4; ++j) {
                    int col = bn + j * 16 + lr;
                    float v = acc[i][j][rr];
                    if (col < N0) {
                        ((u16*)C0)[(size_t)row * N0 + col] = f2b(v);
                    } else {
                        int c1 = col - N0;
                        if (EPI == 3) ((float*)C1)[(size_t)row * N1 + c1] = v;
                        else          ((u16*)C1)[(size_t)row * N1 + c1] = f2b(v);
                    }
                }
            }
        }
    }
}

// ---------------------------------------------------------------------------

extern "C" void kernel_launch(void* const* d_in, const int* in_sizes, int n_in,
                              void* d_out, int out_size, void* d_ws, size_t ws_size,
                              hipStream_t stream) {
    const float* features = (const float*)d_in[0];
    const int*   edge_src = (const int*)d_in[1];
    const int*   edge_dst = (const int*)d_in[2];
    const float* W1s = (const float*)d_in[3];
    const float* W1n = (const float*)d_in[4];
    const float* b1  = (const float*)d_in[5];
    const float* W2s = (const float*)d_in[6];
    const float* W2n = (const float*)d_in[7];
    const float* b2  = (const float*)d_in[8];
    const float* W3s = (const float*)d_in[9];
    const float* W3n = (const float*)d_in[10];
    const float* b3  = (const float*)d_in[11];
    const float* Wres = (const float*)d_in[12];
    const float* bres = (const float*)d_in[13];

    float* out_x   = (float*)d_out;
    float* out_res = out_x + (size_t)N_NODES * OUT_DIM;

    // ---- workspace layout ----
    size_t off = 0;
    auto carve = [&](size_t bytes) {
        size_t p = off;
        off += (bytes + 255) & ~(size_t)255;
        return p;
    };
    size_t o_cnt     = carve((size_t)N_NODES * 4);
    size_t o_rowptr  = carve((size_t)(N_NODES + 1) * 4);
    size_t o_cursor  = carve((size_t)N_NODES * 4);
    size_t o_invdeg  = carve((size_t)N_NODES * 4);
    size_t o_csr     = carve((size_t)N_EDGES * 4);
    size_t o_w1s  = carve((size_t)IN_DIM * H1 * 2);
    size_t o_w1n  = carve((size_t)IN_DIM * H1 * 2);
    size_t o_w23  = carve((size_t)H1 * (H2 + H2) * 2);        // [W2n|W2s] rows, K=H1
    size_t o_w3   = carve((size_t)H2 * (OUT_DIM * 2) * 2);    // [W3n|W3s] rows, K=H2
    size_t o_wrs  = carve((size_t)IN_DIM * OUT_DIM * 2);
    size_t o_regA = carve((size_t)N_NODES * (IN_DIM + IN_DIM) * 2);  // fX+aggF ; later x2
    size_t o_regB = carve((size_t)N_NODES * H1 * 2);                 // x1 ; later Y3+T3(f32)
    size_t o_regC = carve((size_t)N_NODES * H2 * 2);                 // Y2
    size_t o_regD = carve((size_t)N_NODES * H2 * 2);                 // T2
    size_t REQUIRED = off;
    if (ws_size < REQUIRED) return;

    char* W = (char*)d_ws;
    int*   cnt     = (int*)(W + o_cnt);
    int*   row_ptr = (int*)(W + o_rowptr);
    int*   cursor  = (int*)(W + o_cursor);
    float* inv_deg = (float*)(W + o_invdeg);
    int*   csr_src = (int*)(W + o_csr);
    u16* W1sT = (u16*)(W + o_w1s);
    u16* W1nT = (u16*)(W + o_w1n);
    u16* W23T = (u16*)(W + o_w23);
    u16* W3T  = (u16*)(W + o_w3);
    u16* WrsT = (u16*)(W + o_wrs);
    u16* fX   = (u16*)(W + o_regA);
    u16* aggF = fX + (size_t)N_NODES * IN_DIM;
    u16* x2   = (u16*)(W + o_regA);                 // aliases fX+aggF (dead by then)
    u16* x1   = (u16*)(W + o_regB);
    u16* Y3   = (u16*)(W + o_regB);                 // aliases x1 (dead by then)
    float* T3 = (float*)(W + o_regB + (size_t)N_NODES * OUT_DIM * 2);
    u16* Y2   = (u16*)(W + o_regC);
    u16* T2   = (u16*)(W + o_regD);

    const int mt = (N_NODES + 127) / 128;

    // ---- CSR build ----
    zero2_kernel<<<(N_NODES + 255) / 256, 256, 0, stream>>>(cnt, cursor, N_NODES);
    count_deg_kernel<<<(N_EDGES + 255) / 256, 256, 0, stream>>>(edge_dst, cnt, N_EDGES);
    scan_deg_kernel<<<1, 1024, 0, stream>>>(cnt, row_ptr, inv_deg);
    scatter_kernel<<<(N_EDGES + 255) / 256, 256, 0, stream>>>(edge_src, edge_dst, row_ptr,
                                                              cursor, csr_src, N_EDGES);

    // ---- casts / transposes ----
    {
        int n4 = N_NODES * IN_DIM / 4;
        cast_kernel<<<(n4 + 255) / 256, 256, 0, stream>>>((const float4*)features,
                                                          (ushort4*)fX, n4);
    }
    {
        dim3 b(32, 8);
        dim3 g1(H1 / 32, IN_DIM / 32);
        transpose_cast_kernel<<<g1, b, 0, stream>>>(W1s, W1sT, IN_DIM, H1);
        transpose_cast_kernel<<<g1, b, 0, stream>>>(W1n, W1nT, IN_DIM, H1);
        dim3 g2(H2 / 32, H1 / 32);
        transpose_cast_kernel<<<g2, b, 0, stream>>>(W2n, W23T, H1, H2);
        transpose_cast_kernel<<<g2, b, 0, stream>>>(W2s, W23T + (size_t)H2 * H1, H1, H2);
        dim3 g3(OUT_DIM / 32, H2 / 32);
        transpose_cast_kernel<<<g3, b, 0, stream>>>(W3n, W3T, H2, OUT_DIM);
        transpose_cast_kernel<<<g3, b, 0, stream>>>(W3s, W3T + (size_t)OUT_DIM * H2, H2, OUT_DIM);
        dim3 g4(OUT_DIM / 32, IN_DIM / 32);
        transpose_cast_kernel<<<g4, b, 0, stream>>>(Wres, WrsT, IN_DIM, OUT_DIM);
    }

    // ---- residual head: out_res = elu(fX@Wres + bres) (f32) ----
    mfma_gemm_kernel<false, 1><<<1 * mt, 256, 0, stream>>>(
        fX, nullptr, WrsT, nullptr, bres, out_res, nullptr,
        N_NODES, IN_DIM, OUT_DIM, OUT_DIM, 1);

    // ---- layer 1: aggF = mean(fX); x1 = elu(fX@W1s + aggF@W1n + b1) ----
    aggregate_kernel<IN_DIM, 0><<<N_NODES, 256, 0, stream>>>(
        fX, row_ptr, csr_src, inv_deg, nullptr, nullptr, aggF);
    mfma_gemm_kernel<true, 0><<<(H1 / 128) * mt, 256, 0, stream>>>(
        fX, aggF, W1sT, W1nT, b1, x1, nullptr,
        N_NODES, IN_DIM, H1, H1, H1 / 128);

    // ---- layer 2: [Y2|T2] = x1@[W2n|W2s]; x2 = elu(mean(Y2) + T2 + b2) ----
    mfma_gemm_kernel<false, 2><<<((H2 * 2) / 128) * mt, 256, 0, stream>>>(
        x1, nullptr, W23T, nullptr, nullptr, Y2, T2,
        N_NODES, H1, H2 * 2, H2, (H2 * 2) / 128);
    aggregate_kernel<H2, 1><<<N_NODES, 256, 0, stream>>>(
        Y2, row_ptr, csr_src, inv_deg, T2, b2, x2);

    // ---- layer 3: [Y3|T3] = x2@[W3n|W3s]; out_x = elu(mean(Y3) + T3 + b3) ----
    mfma_gemm_kernel<false, 3><<<((OUT_DIM * 2) / 128) * mt, 256, 0, stream>>>(
        x2, nullptr, W3T, nullptr, nullptr, Y3, T3,
        N_NODES, H2, OUT_DIM * 2, OUT_DIM, (OUT_DIM * 2) / 128);
    aggregate_kernel<OUT_DIM, 2><<<N_NODES, 256, 0, stream>>>(
        Y3, row_ptr, csr_src, inv_deg, T3, b3, out_x);
}

// Round 6
// 669.481 us; speedup vs baseline: 2.8617x; 1.2932x over previous
//
#include <hip/hip_runtime.h>
#include <hip/hip_bf16.h>
#include <cstdint>
#include <cstddef>

#define N_NODES 50000
#define N_EDGES 800000
#define IN_DIM 256
#define H1 640
#define H2 320
#define OUT_DIM 128

typedef unsigned short u16;
typedef __attribute__((ext_vector_type(8))) short short8v;   // 8 bf16 = 4 VGPR
typedef __attribute__((ext_vector_type(4))) float float4v;   // MFMA C/D

__device__ __forceinline__ float b2f(u16 u) {
    union { unsigned int i; float f; } v; v.i = ((unsigned int)u) << 16; return v.f;
}
__device__ __forceinline__ u16 f2b(float f) {
    __hip_bfloat16 h = __float2bfloat16(f);
    return *reinterpret_cast<u16*>(&h);
}

// ---------------------------------------------------------------------------
// CSR build
// ---------------------------------------------------------------------------

__global__ void zero2_kernel(int* __restrict__ a, int* __restrict__ b, int n) {
    int i = blockIdx.x * blockDim.x + threadIdx.x;
    if (i < n) { a[i] = 0; b[i] = 0; }
}

__global__ void count_deg_kernel(const int* __restrict__ dst, int* __restrict__ cnt, int nE) {
    int i = blockIdx.x * blockDim.x + threadIdx.x;
    if (i < nE) atomicAdd(&cnt[dst[i]], 1);
}

__global__ __launch_bounds__(1024)
void scan_deg_kernel(const int* __restrict__ cnt, int* __restrict__ row_ptr,
                     float* __restrict__ inv_deg) {
    const int NT = 1024, N = N_NODES;
    const int CH = (N + NT - 1) / NT;
    __shared__ int part[NT];
    int tid = threadIdx.x;
    int s0 = tid * CH;
    int s1 = s0 + CH; if (s1 > N) s1 = N;
    if (s0 > N) s0 = N;
    int s = 0;
    for (int i = s0; i < s1; ++i) s += cnt[i];
    part[tid] = s;
    __syncthreads();
    for (int off = 1; off < NT; off <<= 1) {
        int v = 0;
        if (tid >= off) v = part[tid - off];
        __syncthreads();
        if (tid >= off) part[tid] += v;
        __syncthreads();
    }
    int run = (tid == 0) ? 0 : part[tid - 1];
    for (int i = s0; i < s1; ++i) {
        row_ptr[i] = run;
        int c = cnt[i];
        inv_deg[i] = (c > 0) ? (1.0f / (float)c) : 0.0f;
        run += c;
    }
    if (tid == NT - 1) row_ptr[N] = run;
}

__global__ void scatter_kernel(const int* __restrict__ src, const int* __restrict__ dst,
                               const int* __restrict__ row_ptr, int* __restrict__ cursor,
                               int* __restrict__ csr_src, int nE) {
    int i = blockIdx.x * blockDim.x + threadIdx.x;
    if (i < nE) {
        int d = dst[i];
        int p = atomicAdd(&cursor[d], 1);
        csr_src[row_ptr[d] + p] = src[i];
    }
}

// ---------------------------------------------------------------------------
// f32 -> bf16 cast (vectorized)
// ---------------------------------------------------------------------------

__global__ void cast_kernel(const float4* __restrict__ in, ushort4* __restrict__ out, int n4) {
    int i = blockIdx.x * blockDim.x + threadIdx.x;
    if (i < n4) {
        float4 v = in[i];
        ushort4 o;
        o.x = f2b(v.x); o.y = f2b(v.y); o.z = f2b(v.z); o.w = f2b(v.w);
        out[i] = o;
    }
}

// ---------------------------------------------------------------------------
// Weight transpose + cast:  in f32 [K][N] row-major  ->  out bf16 [N][K]
// ---------------------------------------------------------------------------

__global__ __launch_bounds__(256)
void transpose_cast_kernel(const float* __restrict__ in, u16* __restrict__ out,
                           int K, int N) {
    __shared__ float t[32][33];
    int bx = blockIdx.x * 32;   // N direction
    int by = blockIdx.y * 32;   // K direction
    int x = threadIdx.x;        // 0..31
    int y = threadIdx.y;        // 0..7
#pragma unroll
    for (int i = 0; i < 32; i += 8) {
        int r = by + y + i, c = bx + x;
        if (r < K && c < N) t[y + i][x] = in[(size_t)r * N + c];
    }
    __syncthreads();
#pragma unroll
    for (int i = 0; i < 32; i += 8) {
        int r = bx + y + i, c = by + x;
        if (r < N && c < K) out[(size_t)r * K + c] = f2b(t[x][y + i]);
    }
}

// ---------------------------------------------------------------------------
// Mean aggregation over in-neighbors, edge-parallel per block.
//   cg = t % (D/8) -> 8-col group (16 B vector); es = t / (D/8) -> edge slot
// MODE 0: out_bf16 = sum * w                        (T, bias unused)
// MODE 1: out_bf16 = elu(sum*w + T_bf16 + bias)
// MODE 2: out_f32  = elu(sum*w + T_f32  + bias)
// ---------------------------------------------------------------------------

template<int D, int MODE>
__global__ __launch_bounds__(256)
void aggregate_kernel(const u16* __restrict__ h, const int* __restrict__ row_ptr,
                      const int* __restrict__ csr_src, const float* __restrict__ inv_deg,
                      const void* __restrict__ T, const float* __restrict__ bias,
                      void* __restrict__ out) {
    constexpr int NCG = D / 8;           // col groups (16B each)
    constexpr int NES = 256 / NCG;       // edge slots in flight
    constexpr int ACT = NCG * NES;       // active threads
    __shared__ float red[8][256];
    int node = blockIdx.x;
    int t = threadIdx.x;
    int cg = t % NCG;
    int es = t / NCG;
    int e0 = row_ptr[node], e1 = row_ptr[node + 1];

    float acc[8];
#pragma unroll
    for (int j = 0; j < 8; ++j) acc[j] = 0.0f;

    if (t < ACT) {
        const u16* __restrict__ hb = h + cg * 8;
        int e = e0 + es;
        int sNext = (e < e1) ? csr_src[e] : 0;
        while (e < e1) {
            int s = sNext;
            int e2 = e + NES;
            sNext = (e2 < e1) ? csr_src[e2] : 0;   // prefetch next index
            short8v v = *(const short8v*)(hb + (size_t)s * D);
#pragma unroll
            for (int j = 0; j < 8; ++j) acc[j] += b2f((u16)v[j]);
            e = e2;
        }
    }
#pragma unroll
    for (int j = 0; j < 8; ++j) red[j][t] = acc[j];
    __syncthreads();

    if (t < NCG) {
        float sum[8];
#pragma unroll
        for (int j = 0; j < 8; ++j) sum[j] = red[j][t];
#pragma unroll
        for (int s2 = 1; s2 < NES; ++s2) {
#pragma unroll
            for (int j = 0; j < 8; ++j) sum[j] += red[j][s2 * NCG + t];
        }
        float w = inv_deg[node];
        if (MODE == 0) {
            short8v o;
#pragma unroll
            for (int j = 0; j < 8; ++j) o[j] = (short)f2b(sum[j] * w);
            *(short8v*)((u16*)out + (size_t)node * D + t * 8) = o;
        } else {
            float tv[8];
            if (MODE == 1) {
                short8v tb = *(const short8v*)((const u16*)T + (size_t)node * D + t * 8);
#pragma unroll
                for (int j = 0; j < 8; ++j) tv[j] = b2f((u16)tb[j]);
            } else {
                const float* tp = (const float*)T + (size_t)node * D + t * 8;
                float4 a = *(const float4*)tp, b = *(const float4*)(tp + 4);
                tv[0] = a.x; tv[1] = a.y; tv[2] = a.z; tv[3] = a.w;
                tv[4] = b.x; tv[5] = b.y; tv[6] = b.z; tv[7] = b.w;
            }
            const float* bp = bias + t * 8;
            float4 ba = *(const float4*)bp, bb = *(const float4*)(bp + 4);
            float bv[8] = {ba.x, ba.y, ba.z, ba.w, bb.x, bb.y, bb.z, bb.w};
            float v[8];
#pragma unroll
            for (int j = 0; j < 8; ++j) {
                float x = sum[j] * w + tv[j] + bv[j];
                v[j] = (x > 0.0f) ? x : expm1f(x);
            }
            if (MODE == 1) {
                short8v o;
#pragma unroll
                for (int j = 0; j < 8; ++j) o[j] = (short)f2b(v[j]);
                *(short8v*)((u16*)out + (size_t)node * D + t * 8) = o;
            } else {
                float* op = (float*)out + (size_t)node * D + t * 8;
                *(float4*)op = make_float4(v[0], v[1], v[2], v[3]);
                *(float4*)(op + 4) = make_float4(v[4], v[5], v[6], v[7]);
            }
        }
    }
}

// ---------------------------------------------------------------------------
// MFMA GEMM, m97-style LDS-staged: 128x128 tile, BK=32, double-buffered LDS
// via global_load_lds (width 16), 1 barrier per K-step.
// Both-sides swizzle: stage loads global chunk (c ^ (r&3)) into linear LDS
// chunk c; reads XOR the chunk back -> 4-way instead of 8-way ds conflicts.
//   acc = A0@W0T' [+ A1@W1T']     (W pre-transposed bf16 [N][K])
// EPI 0: C0 bf16 = elu(acc + bias)
// EPI 1: C0 f32  = elu(acc + bias)
// EPI 2: split at N0: C0 bf16 raw | C1 bf16 raw
// EPI 3: split at N0: C0 bf16 raw | C1 f32 raw
// Grid 1D with bijective XCD swizzle; N % 128 == 0, K % 32 == 0, M ragged.
// ---------------------------------------------------------------------------

template<bool DUAL, int EPI>
__global__ __launch_bounds__(256)
void mfma_gemm_kernel(const u16* __restrict__ A0, const u16* __restrict__ A1,
                      const u16* __restrict__ W0T, const u16* __restrict__ W1T,
                      const float* __restrict__ bias,
                      void* __restrict__ C0, void* __restrict__ C1,
                      int M, int K, int N, int N0, int gx) {
    // bijective XCD swizzle (m204)
    int nwg = gridDim.x;
    int d = blockIdx.x;
    int q = nwg >> 3, r8 = nwg & 7;
    int xcd = d & 7, idx = d >> 3;
    int flat = (xcd < r8 ? xcd * (q + 1) : r8 * (q + 1) + (xcd - r8) * q) + idx;
    int bxt = flat % gx, byt = flat / gx;

    int tid = threadIdx.x;
    int wid = tid >> 6;
    int lane = tid & 63;
    int lr = lane & 15;        // row (A) / col (B) within fragment
    int lb = lane >> 4;        // k-chunk 0..3 (8 elems = 16 B each)
    int wr = wid >> 1;         // wave row (M dir)
    int wc = wid & 1;          // wave col (N dir)

    int bm = byt * 128;        // block row base
    int bn = bxt * 128;        // block col base

    // LDS: [buf][A 4096 u16 | B 4096 u16]  = 32 KB total
    __shared__ u16 smem[2 * 8192];

    const int NT0 = K >> 5;                    // K-steps per stream
    const int NT = DUAL ? (NT0 * 2) : NT0;

    // stage K-step kt into buffer buf (fire-and-forget global_load_lds)
    auto stage = [&](int kt, int buf) {
        const u16* Ap; const u16* Wp; int kk;
        if (DUAL && kt >= NT0) { Ap = A1; Wp = W1T; kk = (kt - NT0) << 5; }
        else                   { Ap = A0; Wp = W0T; kk = kt << 5; }
        u16* ab = smem + buf * 8192;
#pragma unroll
        for (int i = 0; i < 2; ++i) {
            int cc = tid + i * 256;            // 0..511 : 16B chunk id
            int rr = cc >> 2, c = cc & 3;
            int cg = c ^ (rr & 3);             // pre-swizzled global source
            int grow = bm + rr; if (grow > M - 1) grow = M - 1;
            const u16* gp = Ap + (size_t)grow * K + kk + cg * 8;
            __builtin_amdgcn_global_load_lds(
                (const __attribute__((address_space(1))) void*)gp,
                (__attribute__((address_space(3))) void*)(ab + cc * 8), 16, 0, 0);
        }
#pragma unroll
        for (int i = 0; i < 2; ++i) {
            int cc = tid + i * 256;
            int rr = cc >> 2, c = cc & 3;
            int cg = c ^ (rr & 3);
            int gcol = bn + rr;                // B "row" = output col, never OOB
            const u16* gp = Wp + (size_t)gcol * K + kk + cg * 8;
            __builtin_amdgcn_global_load_lds(
                (const __attribute__((address_space(1))) void*)gp,
                (__attribute__((address_space(3))) void*)(ab + 4096 + cc * 8), 16, 0, 0);
        }
    };

    float4v acc[4][4] = {};

    int cur = 0;
    stage(0, 0);
    __syncthreads();

    int sw = lb ^ (lr & 3);                    // read-side chunk XOR
    for (int kt = 0; kt < NT; ++kt) {
        if (kt + 1 < NT) stage(kt + 1, cur ^ 1);
        const u16* ab = smem + cur * 8192;
        const u16* bb = ab + 4096;
        short8v af[4], bf[4];
#pragma unroll
        for (int i = 0; i < 4; ++i)
            af[i] = *(const short8v*)(ab + (wr * 64 + i * 16 + lr) * 32 + sw * 8);
#pragma unroll
        for (int j = 0; j < 4; ++j)
            bf[j] = *(const short8v*)(bb + (wc * 64 + j * 16 + lr) * 32 + sw * 8);
#pragma unroll
        for (int i = 0; i < 4; ++i)
#pragma unroll
            for (int j = 0; j < 4; ++j)
                acc[i][j] = __builtin_amdgcn_mfma_f32_16x16x32_bf16(
                    af[i], bf[j], acc[i][j], 0, 0, 0);
        __syncthreads();
        cur ^= 1;
    }

    // epilogue: C[bm + wr*64 + i*16 + lb*4 + rr][bn + wc*64 + j*16 + lr]
    int bmw = bm + wr * 64, bnw = bn + wc * 64;
    if (EPI <= 1) {
        float bi[4];
#pragma unroll
        for (int j = 0; j < 4; ++j) bi[j] = bias[bnw + j * 16 + lr];
#pragma unroll
        for (int i = 0; i < 4; ++i) {
#pragma unroll
            for (int rr = 0; rr < 4; ++rr) {
                int row = bmw + i * 16 + lb * 4 + rr;
                if (row >= M) continue;
#pragma unroll
                for (int j = 0; j < 4; ++j) {
                    int col = bnw + j * 16 + lr;
                    float v = acc[i][j][rr] + bi[j];
                    v = (v > 0.0f) ? v : expm1f(v);
                    if (EPI == 1) ((float*)C0)[(size_t)row * N + col] = v;
                    else          ((u16*)C0)[(size_t)row * N + col] = f2b(v);
                }
            }
        }
    } else {
        int N1 = N - N0;
#pragma unroll
        for (int i = 0; i < 4; ++i) {
#pragma unroll
            for (int rr = 0; rr < 4; ++rr) {
                int row = bmw + i * 16 + lb * 4 + rr;
                if (row >= M) continue;
#pragma unroll
                for (int j = 0; j < 4; ++j) {
                    int col = bnw + j * 16 + lr;
                    float v = acc[i][j][rr];
                    if (col < N0) {
                        ((u16*)C0)[(size_t)row * N0 + col] = f2b(v);
                    } else {
                        int c1 = col - N0;
                        if (EPI == 3) ((float*)C1)[(size_t)row * N1 + c1] = v;
                        else          ((u16*)C1)[(size_t)row * N1 + c1] = f2b(v);
                    }
                }
            }
        }
    }
}

// ---------------------------------------------------------------------------

extern "C" void kernel_launch(void* const* d_in, const int* in_sizes, int n_in,
                              void* d_out, int out_size, void* d_ws, size_t ws_size,
                              hipStream_t stream) {
    const float* features = (const float*)d_in[0];
    const int*   edge_src = (const int*)d_in[1];
    const int*   edge_dst = (const int*)d_in[2];
    const float* W1s = (const float*)d_in[3];
    const float* W1n = (const float*)d_in[4];
    const float* b1  = (const float*)d_in[5];
    const float* W2s = (const float*)d_in[6];
    const float* W2n = (const float*)d_in[7];
    const float* b2  = (const float*)d_in[8];
    const float* W3s = (const float*)d_in[9];
    const float* W3n = (const float*)d_in[10];
    const float* b3  = (const float*)d_in[11];
    const float* Wres = (const float*)d_in[12];
    const float* bres = (const float*)d_in[13];

    float* out_x   = (float*)d_out;
    float* out_res = out_x + (size_t)N_NODES * OUT_DIM;

    // ---- workspace layout ----
    size_t off = 0;
    auto carve = [&](size_t bytes) {
        size_t p = off;
        off += (bytes + 255) & ~(size_t)255;
        return p;
    };
    size_t o_cnt     = carve((size_t)N_NODES * 4);
    size_t o_rowptr  = carve((size_t)(N_NODES + 1) * 4);
    size_t o_cursor  = carve((size_t)N_NODES * 4);
    size_t o_invdeg  = carve((size_t)N_NODES * 4);
    size_t o_csr     = carve((size_t)N_EDGES * 4);
    size_t o_w1s  = carve((size_t)IN_DIM * H1 * 2);
    size_t o_w1n  = carve((size_t)IN_DIM * H1 * 2);
    size_t o_w23  = carve((size_t)H1 * (H2 + H2) * 2);        // [W2n|W2s] rows, K=H1
    size_t o_w3   = carve((size_t)H2 * (OUT_DIM * 2) * 2);    // [W3n|W3s] rows, K=H2
    size_t o_wrs  = carve((size_t)IN_DIM * OUT_DIM * 2);
    size_t o_regA = carve((size_t)N_NODES * (IN_DIM + IN_DIM) * 2);  // fX+aggF ; later x2
    size_t o_regB = carve((size_t)N_NODES * H1 * 2);                 // x1 ; later Y3+T3(f32)
    size_t o_regC = carve((size_t)N_NODES * H2 * 2);                 // Y2
    size_t o_regD = carve((size_t)N_NODES * H2 * 2);                 // T2
    size_t REQUIRED = off;
    if (ws_size < REQUIRED) return;

    char* W = (char*)d_ws;
    int*   cnt     = (int*)(W + o_cnt);
    int*   row_ptr = (int*)(W + o_rowptr);
    int*   cursor  = (int*)(W + o_cursor);
    float* inv_deg = (float*)(W + o_invdeg);
    int*   csr_src = (int*)(W + o_csr);
    u16* W1sT = (u16*)(W + o_w1s);
    u16* W1nT = (u16*)(W + o_w1n);
    u16* W23T = (u16*)(W + o_w23);
    u16* W3T  = (u16*)(W + o_w3);
    u16* WrsT = (u16*)(W + o_wrs);
    u16* fX   = (u16*)(W + o_regA);
    u16* aggF = fX + (size_t)N_NODES * IN_DIM;
    u16* x2   = (u16*)(W + o_regA);                 // aliases fX+aggF (dead by then)
    u16* x1   = (u16*)(W + o_regB);
    u16* Y3   = (u16*)(W + o_regB);                 // aliases x1 (dead by then)
    float* T3 = (float*)(W + o_regB + (size_t)N_NODES * OUT_DIM * 2);
    u16* Y2   = (u16*)(W + o_regC);
    u16* T2   = (u16*)(W + o_regD);

    const int mt = (N_NODES + 127) / 128;

    // ---- CSR build ----
    zero2_kernel<<<(N_NODES + 255) / 256, 256, 0, stream>>>(cnt, cursor, N_NODES);
    count_deg_kernel<<<(N_EDGES + 255) / 256, 256, 0, stream>>>(edge_dst, cnt, N_EDGES);
    scan_deg_kernel<<<1, 1024, 0, stream>>>(cnt, row_ptr, inv_deg);
    scatter_kernel<<<(N_EDGES + 255) / 256, 256, 0, stream>>>(edge_src, edge_dst, row_ptr,
                                                              cursor, csr_src, N_EDGES);

    // ---- casts / transposes ----
    {
        int n4 = N_NODES * IN_DIM / 4;
        cast_kernel<<<(n4 + 255) / 256, 256, 0, stream>>>((const float4*)features,
                                                          (ushort4*)fX, n4);
    }
    {
        dim3 b(32, 8);
        dim3 g1(H1 / 32, IN_DIM / 32);
        transpose_cast_kernel<<<g1, b, 0, stream>>>(W1s, W1sT, IN_DIM, H1);
        transpose_cast_kernel<<<g1, b, 0, stream>>>(W1n, W1nT, IN_DIM, H1);
        dim3 g2(H2 / 32, H1 / 32);
        transpose_cast_kernel<<<g2, b, 0, stream>>>(W2n, W23T, H1, H2);
        transpose_cast_kernel<<<g2, b, 0, stream>>>(W2s, W23T + (size_t)H2 * H1, H1, H2);
        dim3 g3(OUT_DIM / 32, H2 / 32);
        transpose_cast_kernel<<<g3, b, 0, stream>>>(W3n, W3T, H2, OUT_DIM);
        transpose_cast_kernel<<<g3, b, 0, stream>>>(W3s, W3T + (size_t)OUT_DIM * H2, H2, OUT_DIM);
        dim3 g4(OUT_DIM / 32, IN_DIM / 32);
        transpose_cast_kernel<<<g4, b, 0, stream>>>(Wres, WrsT, IN_DIM, OUT_DIM);
    }

    // ---- residual head: out_res = elu(fX@Wres + bres) (f32) ----
    mfma_gemm_kernel<false, 1><<<1 * mt, 256, 0, stream>>>(
        fX, nullptr, WrsT, nullptr, bres, out_res, nullptr,
        N_NODES, IN_DIM, OUT_DIM, OUT_DIM, 1);

    // ---- layer 1: aggF = mean(fX); x1 = elu(fX@W1s + aggF@W1n + b1) ----
    aggregate_kernel<IN_DIM, 0><<<N_NODES, 256, 0, stream>>>(
        fX, row_ptr, csr_src, inv_deg, nullptr, nullptr, aggF);
    mfma_gemm_kernel<true, 0><<<(H1 / 128) * mt, 256, 0, stream>>>(
        fX, aggF, W1sT, W1nT, b1, x1, nullptr,
        N_NODES, IN_DIM, H1, H1, H1 / 128);

    // ---- layer 2: [Y2|T2] = x1@[W2n|W2s]; x2 = elu(mean(Y2) + T2 + b2) ----
    mfma_gemm_kernel<false, 2><<<((H2 * 2) / 128) * mt, 256, 0, stream>>>(
        x1, nullptr, W23T, nullptr, nullptr, Y2, T2,
        N_NODES, H1, H2 * 2, H2, (H2 * 2) / 128);
    aggregate_kernel<H2, 1><<<N_NODES, 256, 0, stream>>>(
        Y2, row_ptr, csr_src, inv_deg, T2, b2, x2);

    // ---- layer 3: [Y3|T3] = x2@[W3n|W3s]; out_x = elu(mean(Y3) + T3 + b3) ----
    mfma_gemm_kernel<false, 3><<<((OUT_DIM * 2) / 128) * mt, 256, 0, stream>>>(
        x2, nullptr, W3T, nullptr, nullptr, Y3, T3,
        N_NODES, H2, OUT_DIM * 2, OUT_DIM, (OUT_DIM * 2) / 128);
    aggregate_kernel<OUT_DIM, 2><<<N_NODES, 256, 0, stream>>>(
        Y3, row_ptr, csr_src, inv_deg, T3, b3, out_x);
}